// Round 11
// baseline (8062.476 us; speedup 1.0000x reference)
//
#include <hip/hip_runtime.h>

namespace {

constexpr int NROWS = 256, LSTEPS = 512, IN = 64, LAT = 32, HID = 128;

typedef _Float16 h2 __attribute__((ext_vector_type(2)));
typedef _Float16 h8 __attribute__((ext_vector_type(8)));

__device__ __forceinline__ float fast_sigmoid(float x) {
    return __fdividef(1.f, 1.f + __expf(-x));
}
__device__ __forceinline__ float fast_softplus(float x) {
    return fmaxf(x, 0.f) + __logf(1.f + __expf(-fabsf(x)));
}
__device__ __forceinline__ float fast_tanh(float x) {
    float e = __expf(-2.f * fabsf(x));
    return copysignf(__fdividef(1.f - e, 1.f + e), x);
}
__device__ __forceinline__ float dot2(h2 w, h2 a, float c) {
    return __builtin_amdgcn_fdot2(w, a, c, false);   // v_dot2_f32_f16
}
__device__ __forceinline__ h2 packw(float a, float b) {
    h2 r; r[0] = (_Float16)a; r[1] = (_Float16)b; return r;
}
// LDS-visibility barrier (global loads/stores stay in flight in vmcnt).
__device__ __forceinline__ void soft_barrier() {
    asm volatile("s_waitcnt lgkmcnt(0)\n\ts_barrier" ::: "memory");
}
// NH2 h2 activations from LDS via 16B reads; h2 regs alias the b128 dwords.
template<int NH2>
__device__ __forceinline__ void lda(const _Float16* p, h2* o) {
#pragma unroll
    for (int i = 0; i < NH2 / 4; ++i) {
        h8 b = *(const h8*)(p + 8 * i);
        o[4*i+0] = __builtin_shufflevector(b, b, 0, 1);
        o[4*i+1] = __builtin_shufflevector(b, b, 2, 3);
        o[4*i+2] = __builtin_shufflevector(b, b, 4, 5);
        o[4*i+3] = __builtin_shufflevector(b, b, 6, 7);
    }
}
template<int NP>
__device__ __forceinline__ float dotw(const h2* w, const h2* a, float init) {
    float s0 = init, s1 = 0.f, s2 = 0.f, s3 = 0.f;
#pragma unroll
    for (int i = 0; i < NP / 4; ++i) {
        s0 = dot2(w[4*i+0], a[4*i+0], s0);
        s1 = dot2(w[4*i+1], a[4*i+1], s1);
        s2 = dot2(w[4*i+2], a[4*i+2], s2);
        s3 = dot2(w[4*i+3], a[4*i+3], s3);
    }
    return (s0 + s1) + (s2 + s3);
}

} // namespace

// 512 threads (2 waves/SIMD -> 256-VGPR budget: weights stay architectural).
// One block per batch row. t = u*4 + q: gate unit u in [0,128), K-quarter q.
// 3-barrier step:
//  A: gh r/z/n (all) | qzcx -> z (t<256, 8-lane shfl) | pxcz_h partial (t>=256)
//  B: pxcz_z + shfl -> x_gen (t>=256) | next-x staging (t<64)
//  C: gi x+z quarters; fold gi_r/gi_z into gh partials; 4x shfl-reduce;
//     lane q==0: GRU gates, exact-f32 h, write h + output.
// R10 bug fixed here: pxcz_z must cover 8 pairs per K-half (z[16kh,16kh+16)),
// not 4 — R10 dropped half the z rows of Wp (absmax 4.9e-2).
__global__ __launch_bounds__(512)
__attribute__((amdgpu_waves_per_eu(2, 2)))
void vrnn_kernel(
    const float* __restrict__ X, const float* __restrict__ EZ, const float* __restrict__ EX,
    const float* __restrict__ Wq, const float* __restrict__ bq,
    const float* __restrict__ Wp, const float* __restrict__ bp,
    const float* __restrict__ Wih, const float* __restrict__ Whh,
    const float* __restrict__ bih, const float* __restrict__ bhh,
    float* __restrict__ out)
{
    __shared__ alignas(16) _Float16 XH[192];   // [ x(64) | h(128) ]
    __shared__ alignas(16) _Float16 ZH[32];    // z_gen
    __shared__ alignas(16) _Float16 XZ[64];    // x_gen

    const int t = threadIdx.x, n = blockIdx.x;
    const int u = t >> 2, q = t & 3;
    const bool lo = (t < 256);

    h2 wgh[48];    // gh: 3 gates x 16 pairs (K-quarter q)
    h2 wgi[36];    // gi: 3 gates x (8 x-pairs + 4 z-pairs)
    h2 wsp[40];    // t<256: qzcx 24 | t>=256: pxcz_h 32 + pxcz_z 8

    // ---- one-time weight packing ----
#pragma unroll
    for (int g = 0; g < 3; ++g) {
        const int col = g * 128 + u;
#pragma unroll
        for (int p = 0; p < 16; ++p) { int k = 32*q + 2*p;
            wgh[g*16+p] = packw(Whh[k*384 + col], Whh[(k+1)*384 + col]); }
#pragma unroll
        for (int p = 0; p < 8; ++p) { int k = 16*q + 2*p;
            wgi[g*12+p] = packw(Wih[k*384 + col], Wih[(k+1)*384 + col]); }
#pragma unroll
        for (int p = 0; p < 4; ++p) { int k = 64 + 8*q + 2*p;
            wgi[g*12+8+p] = packw(Wih[k*384 + col], Wih[(k+1)*384 + col]); }
    }

    int jq = 0, jp = 0;
    float bqm=0, bqr=0, bpm=0, bpr=0;
    if (lo) {   // qzcx: 8-lane group j = t>>3; l8 = mr*4 + ks
        jq = t >> 3;
        const int l8 = t & 7, mr = l8 >> 2, ks = l8 & 3;
        const int o = jq + 32 * mr;
#pragma unroll
        for (int p = 0; p < 24; ++p) { int k = 48*ks + 2*p;
            wsp[p] = packw(Wq[k*64 + o], Wq[(k+1)*64 + o]); }
        if (l8 == 0) { bqm = bq[jq]; bqr = bq[32 + jq]; }
    } else {    // pxcz: 4-lane group j = (t-256)>>2; lanes: q = kh*2 + mr
        jp = (t - 256) >> 2;
        const int mr = t & 1, kh = q >> 1;
        const int o = jp + 64 * mr;
#pragma unroll
        for (int p = 0; p < 32; ++p) { int k = 32 + 64*kh + 2*p;   // h rows
            wsp[p] = packw(Wp[k*128 + o], Wp[(k+1)*128 + o]); }
#pragma unroll
        for (int p = 0; p < 8; ++p) { int k = 16*kh + 2*p;         // z rows (ALL 32)
            wsp[32+p] = packw(Wp[k*128 + o], Wp[(k+1)*128 + o]); }
        if ((t & 3) == 0) { bpm = bp[jp]; bpr = bp[64 + jp]; }
    }
    float bh0=0, bh1=0, bh2=0, bi0=0, bi1=0, bi2=0;
    if (q == 0) {
        bh0 = bhh[u]; bh1 = bhh[128+u]; bh2 = bhh[256+u];
        bi0 = bih[u]; bi1 = bih[128+u]; bi2 = bih[256+u];
    }

    // ---- state + prefetch pipeline ----
    const float* Xrow = X + (size_t)n * LSTEPS * IN;
    float* orow = out + (size_t)n * LSTEPS * HID + u;
    const float* ezp = EZ + n * LAT + jq;          // z-writers (t<256, t&7==0)
    const float* exp_ = EX + n * IN + jp;          // x_gen-writers (t>=256, t&3==0)
    float hprev = 0.f;
    float ez = 0.f, ex = 0.f, ezn = 0.f, exn = 0.f, xn = 0.f;
    if (lo && (t & 7) == 0) ez = ezp[0];
    if (!lo && (t & 3) == 0) ex = exp_[0];
    ezp += NROWS * LAT; exp_ += NROWS * IN;        // -> step 1
    if (t < 128) XH[64 + t] = (_Float16)0.f;
    if (t < 64)  XH[t] = (_Float16)Xrow[t];
    __syncthreads();

    float g0 = 0.f, g1 = 0.f, g2 = 0.f, ph = 0.f;

    for (int l = 0; l < LSTEPS; ++l) {
        // prefetch next-step globals (off critical path)
        if (l + 1 < LSTEPS) {
            if (lo && (t & 7) == 0) ezn = ezp[0];
            if (!lo && (t & 3) == 0) exn = exp_[0];
            if (t < 64) xn = Xrow[(size_t)(l + 1) * IN + t];
        }
        ezp += NROWS * LAT; exp_ += NROWS * IN;

        // ---------------- Phase A ----------------
        if (lo) {
            const int ks = t & 3;
            h2 aq[24]; lda<24>(XH + 48 * ks, aq);
            float qd = dotw<24>(wsp, aq, 0.f);
            h2 ah[16]; lda<16>(XH + 64 + 32 * q, ah);
            g0 = dotw<16>(wgh +  0, ah, 0.f);
            g1 = dotw<16>(wgh + 16, ah, 0.f);
            g2 = dotw<16>(wgh + 32, ah, 0.f);
            qd += __shfl_xor(qd, 1);
            qd += __shfl_xor(qd, 2);
            float other = __shfl_xor(qd, 4);       // mean <-> raw
            if ((t & 7) == 0) {
                float z = (qd + bqm) + fast_softplus(other + bqr) * ez;
                ZH[jq] = (_Float16)z;
            }
        } else {
            const int kh = q >> 1;
            h2 ah2[32]; lda<32>(XH + 64 + 64 * kh, ah2);
            ph = dotw<32>(wsp, ah2, 0.f);
            const h2* ahq = ah2 + 16 * (q & 1);    // gh quarter q within half kh
            g0 = dotw<16>(wgh +  0, ahq, 0.f);
            g1 = dotw<16>(wgh + 16, ahq, 0.f);
            g2 = dotw<16>(wgh + 32, ahq, 0.f);
        }
        soft_barrier();

        // ---------------- Phase B ----------------
        if (!lo) {
            const int kh = q >> 1;
            h2 az[8]; lda<8>(ZH + 16 * kh, az);    // z[16kh .. 16kh+16)
            float tot = dotw<8>(wsp + 32, az, ph);
            tot += __shfl_xor(tot, 2);             // combine K-halves
            float other = __shfl_xor(tot, 1);      // mean <-> raw
            if ((t & 3) == 0) {
                float xg = (tot + bpm) + fast_softplus(other + bpr) * ex;
                XZ[jp] = (_Float16)xg;
            }
        } else if (t < 64 && l + 1 < LSTEPS) {
            XH[t] = (_Float16)xn;                  // stage next x
        }
        soft_barrier();

        // ---------------- Phase C: gi + reduce + gates ----------------
        {
            h2 ax[8];  lda<8>(XZ + 16 * q, ax);
            h2 az2[4]; lda<4>(ZH + 8 * q, az2);
            float gi0 = dotw<8>(wgi +  0, ax, 0.f); gi0 = dotw<4>(wgi +  8, az2, gi0);
            float gi1 = dotw<8>(wgi + 12, ax, 0.f); gi1 = dotw<4>(wgi + 20, az2, gi1);
            float gi2 = dotw<8>(wgi + 24, ax, 0.f); gi2 = dotw<4>(wgi + 32, az2, gi2);
            float s0 = g0 + gi0;                   // r: gh+gi fold
            float s1 = g1 + gi1;                   // z: gh+gi fold
            float s2 = g2;                         // n: gh alone
            float s3 = gi2;                        // n: gi alone
            s0 += __shfl_xor(s0, 1); s0 += __shfl_xor(s0, 2);
            s1 += __shfl_xor(s1, 1); s1 += __shfl_xor(s1, 2);
            s2 += __shfl_xor(s2, 1); s2 += __shfl_xor(s2, 2);
            s3 += __shfl_xor(s3, 1); s3 += __shfl_xor(s3, 2);
            if (q == 0) {
                float rr = fast_sigmoid(s0 + bi0 + bh0);
                float zg = fast_sigmoid(s1 + bi1 + bh1);
                float nn = fast_tanh(fmaf(rr, s2 + bh2, s3 + bi2));
                float h = fmaf(zg, hprev - nn, nn);   // (1-z)*n + z*h
                hprev = h;
                XH[64 + u] = (_Float16)h;
                orow[(size_t)l * HID] = h;
            }
        }
        ez = ezn; ex = exn;
        soft_barrier();
    }

    if (q == 0)
        out[(size_t)NROWS * LSTEPS * HID + (size_t)n * HID + u] = hprev;
}

extern "C" void kernel_launch(void* const* d_in, const int* in_sizes, int n_in,
                              void* d_out, int out_size, void* d_ws, size_t ws_size,
                              hipStream_t stream) {
    const float* X   = (const float*)d_in[0];
    const float* EZ  = (const float*)d_in[1];
    const float* EX  = (const float*)d_in[2];
    const float* Wq  = (const float*)d_in[3];
    const float* bq  = (const float*)d_in[4];
    const float* Wp  = (const float*)d_in[5];
    const float* bp  = (const float*)d_in[6];
    const float* Wih = (const float*)d_in[7];
    const float* Whh = (const float*)d_in[8];
    const float* bih = (const float*)d_in[9];
    const float* bhh = (const float*)d_in[10];
    float* out = (float*)d_out;

    vrnn_kernel<<<dim3(NROWS), dim3(512), 0, stream>>>(
        X, EZ, EX, Wq, bq, Wp, bp, Wih, Whh, bih, bhh, out);
}